// Round 4
// baseline (2157.335 us; speedup 1.0000x reference)
//
#include <hip/hip_runtime.h>

#define BB 64
#define TT 512
#define EE 128
#define HH 512
#define NGRP 4
#define BG 16
#define JW 16
#define NSLOT 132
#define LDH 520   // 512 + 8 fp16 pad
#define LDE 136   // 128 + 8

typedef _Float16 f16;
typedef f16 f16x8 __attribute__((ext_vector_type(8)));
typedef float floatx4 __attribute__((ext_vector_type(4)));
typedef unsigned u32x4 __attribute__((ext_vector_type(4)));
typedef unsigned long long u64;

__device__ __forceinline__ float sigmf(float x) { return 1.f / (1.f + __expf(-x)); }
__device__ __forceinline__ float tanhfast(float x) { return 2.f / (1.f + __expf(-2.f * x)) - 1.f; }

// L1-bypassing, L2-hitting load (SE-scope). Semantics runtime-validated; on any
// mismatch the probe fails and we fall back to the agent-scope (L3) path.
__device__ __forceinline__ unsigned ld_sc0_u32(const unsigned* p) {
  unsigned v;
  asm volatile("global_load_dword %0, %1, off sc0\n\ts_waitcnt vmcnt(0)"
               : "=v"(v) : "v"(p) : "memory");
  return v;
}

__device__ __forceinline__ unsigned hs_poll(const unsigned* p, unsigned ph) {
  for (;;) {
    unsigned v = __hip_atomic_load(p, __ATOMIC_RELAXED, __HIP_MEMORY_SCOPE_AGENT);
    if (__all(v >= ph)) return v;
    __builtin_amdgcn_s_sleep(2);
  }
}

// ---------------- slot map ----------------
__global__ __launch_bounds__(64) void build_map(const int* __restrict__ bnd,
                                                int* __restrict__ slotmap)
{
  __shared__ unsigned char need[TT];
  const int b = blockIdx.x;
  for (int i = threadIdx.x; i < TT; i += 64) need[i] = 0;
  __syncthreads();
  {
    const int w = threadIdx.x;
    const int iv = bnd[b * 65 + w];
    const int jv = bnd[b * 65 + w + 1];
    if (iv != -1 && jv != -1) {
      int ic = iv < 0 ? 0 : (iv > TT - 1 ? TT - 1 : iv);
      int jc = jv < 0 ? 0 : (jv > TT - 1 ? TT - 1 : jv);
      need[ic] = 1;
      need[jc] = 1;
    }
  }
  __syncthreads();
  if (threadIdx.x == 0) {
    int c = 0;
    for (int t = 0; t < TT; ++t) slotmap[b * TT + t] = need[t] ? (c++) : -1;
  }
}

// ---------------- persistent bidirectional LSTM scan ----------------
__global__ __launch_bounds__(256, 1) void lstm_scan(
    const int* __restrict__ ids, const int* __restrict__ maskI,
    const float* __restrict__ emb,
    const float* __restrict__ Wih_f, const float* __restrict__ Whh_f, const float* __restrict__ b_f,
    const float* __restrict__ Wih_b, const float* __restrict__ Whh_b, const float* __restrict__ b_b,
    const int* __restrict__ slotmap,
    f16* __restrict__ h_g,        // [2 buf][2 dir][NGRP][BG][HH] fp16 ping-pong
    f16* __restrict__ hist,       // [2 dir][BB][NSLOT][HH] fp16
    unsigned* __restrict__ flags, // [8*32] slots, 128B apart
    unsigned* __restrict__ hsb,   // handshake slots, 128B apart
    unsigned* __restrict__ probe) // [8] probe words, 128B apart
{
  __shared__ f16 sH[BG * LDH];
  __shared__ f16 sX[BG * LDE];
  __shared__ f16 hOut[BG * JW];
  __shared__ float sMask[BG];
  __shared__ int sSlot[BG];
  __shared__ int sFast;

  const int tid = threadIdx.x;
  const int bid = blockIdx.x;
  const int dom = bid & 7;
  const int slice = bid >> 3;          // 0..31
  const int dir = dom & 1;
  const int grp = dom >> 1;
  const int lane = tid & 63;
  const int wave = tid >> 6;

  // ===== runtime probe: can this domain exchange through one L2? =====
  {
    unsigned* myhs = hsb + (dom * 32 + slice) * 32;
    const unsigned* plhs = hsb + (dom * 32 + (lane & 31)) * 32;
    unsigned* pr = probe + dom * 32;
    unsigned ph = 0;
    bool ok = true;
    for (int k = 0; k < 4; ++k) {
      const unsigned expv = (unsigned)(k + 1) * 0x1111u;
      // round A: everyone done with previous read
      ph += 0x100;
      if (tid == 0) __hip_atomic_store(myhs, ph, __ATOMIC_RELAXED, __HIP_MEMORY_SCOPE_AGENT);
      if (wave == 0) hs_poll(plhs, ph);
      __syncthreads();
      // writer plain-stores into (its) L2
      if (tid == 0 && slice == 0) *pr = expv;
      asm volatile("s_waitcnt vmcnt(0)" ::: "memory");
      // round B: writer's arrival implies data landed
      ph += 0x100;
      if (tid == 0) __hip_atomic_store(myhs, ph, __ATOMIC_RELAXED, __HIP_MEMORY_SCOPE_AGENT);
      if (wave == 0) {
        hs_poll(plhs, ph);
        const unsigned v = ld_sc0_u32(pr);
        ok = ok && (v == expv);
      }
      __syncthreads();
    }
    ph += 0x100;
    if (tid == 0) __hip_atomic_store(myhs, ph | (ok ? 1u : 0u),
                                     __ATOMIC_RELAXED, __HIP_MEMORY_SCOPE_AGENT);
    if (wave == 0) {
      const unsigned v = hs_poll(plhs, ph);
      const int f = __all((v & 1u) != 0u) ? 1 : 0;
      if (lane == 0) sFast = f;
    }
    __syncthreads();
  }
  const bool FASTM = (sFast != 0);

  const float* Wih = dir ? Wih_b : Wih_f;
  const float* Whh = dir ? Whh_b : Whh_f;
  const float* bv  = dir ? b_b   : b_f;

  const int rloc = lane & 15;
  const int kg   = lane >> 4;
  const int rglob = wave * 16 + rloc;  // gate-row in slice, r = jloc*4 + q
  const int jloc  = rglob >> 2;
  const int q     = rglob & 3;         // 0=i,1=f,2=g,3=o
  const int mbase = kg * 4;
  const int growL = q * HH + slice * JW + jloc;

  // --- preload step-invariant weights into registers (fp32 -> fp16) ---
  f16x8 wh[16];
  {
    const float* wr = Whh + (size_t)growL * HH + kg * 8;
    #pragma unroll
    for (int kk = 0; kk < 16; ++kk) {
      float4 a0 = *(const float4*)(wr + kk * 32);
      float4 a1 = *(const float4*)(wr + kk * 32 + 4);
      f16x8 v;
      v[0]=(f16)a0.x; v[1]=(f16)a0.y; v[2]=(f16)a0.z; v[3]=(f16)a0.w;
      v[4]=(f16)a1.x; v[5]=(f16)a1.y; v[6]=(f16)a1.z; v[7]=(f16)a1.w;
      wh[kk] = v;
    }
  }
  f16x8 wx[4];
  {
    const float* wr = Wih + (size_t)growL * EE + kg * 8;
    #pragma unroll
    for (int kk = 0; kk < 4; ++kk) {
      float4 a0 = *(const float4*)(wr + kk * 32);
      float4 a1 = *(const float4*)(wr + kk * 32 + 4);
      f16x8 v;
      v[0]=(f16)a0.x; v[1]=(f16)a0.y; v[2]=(f16)a0.z; v[3]=(f16)a0.w;
      v[4]=(f16)a1.x; v[5]=(f16)a1.y; v[6]=(f16)a1.z; v[7]=(f16)a1.w;
      wx[kk] = v;
    }
  }
  const float bsc = bv[growL];

  float cc[4] = {0.f, 0.f, 0.f, 0.f};
  float hh[4] = {0.f, 0.f, 0.f, 0.f};

  const int xrow = tid >> 4;           // x staging: batch row
  const int xc0 = (tid & 15) * 8;      // x staging: col base

  // ---- prologue: stage x/mask/slot for s=0 ----
  {
    const int t0 = dir ? (TT - 1) : 0;
    const int b = grp * BG + xrow;
    const int idx = ids[b * TT + t0];
    float4 x0 = *(const float4*)(emb + (size_t)idx * EE + xc0);
    float4 x1 = *(const float4*)(emb + (size_t)idx * EE + xc0 + 4);
    f16x8 xv;
    xv[0]=(f16)x0.x; xv[1]=(f16)x0.y; xv[2]=(f16)x0.z; xv[3]=(f16)x0.w;
    xv[4]=(f16)x1.x; xv[5]=(f16)x1.y; xv[6]=(f16)x1.z; xv[7]=(f16)x1.w;
    *(f16x8*)(sX + xrow * LDE + xc0) = xv;
    if (tid < BG) {
      const int b2 = grp * BG + tid;
      sMask[tid] = (float)maskI[b2 * TT + t0];
      sSlot[tid] = slotmap[b2 * TT + t0];
    }
  }

  for (int s = 0; s < TT; ++s) {
    // ---- stage h_s into LDS ----
    if (s == 0) {
      for (int e = tid; e < BG * 64; e += 256) {
        const int row = e >> 6, ch = e & 63;
        uint4 z = make_uint4(0u, 0u, 0u, 0u);
        *(uint4*)(sH + row * LDH + ch * 8) = z;
      }
    } else if (FASTM) {
      const f16* hq = h_g + ((size_t)(((s & 1) * 2 + dir) * NGRP + grp)) * BG * HH;
      u32x4 hv[4];
      #pragma unroll
      for (int p = 0; p < 4; ++p) {
        const f16* src = hq + (size_t)(p * 256 + tid) * 8;   // 16B chunks
        asm volatile("global_load_dwordx4 %0, %1, off sc0" : "=v"(hv[p]) : "v"(src));
      }
      asm volatile("s_waitcnt vmcnt(0)" ::: "memory");
      __builtin_amdgcn_sched_barrier(0);
      #pragma unroll
      for (int p = 0; p < 4; ++p) {
        const int e = p * 256 + tid;      // 64 16B-chunks per 512-f16 row
        const int row = e >> 6, ch = e & 63;
        *(u32x4*)(sH + row * LDH + ch * 8) = hv[p];
      }
    } else {
      const u64* hq = (const u64*)(h_g + ((size_t)(((s & 1) * 2 + dir) * NGRP + grp)) * BG * HH);
      u64 v[8];
      #pragma unroll
      for (int p = 0; p < 8; ++p)
        v[p] = __hip_atomic_load(hq + p * 256 + tid, __ATOMIC_RELAXED, __HIP_MEMORY_SCOPE_AGENT);
      #pragma unroll
      for (int p = 0; p < 8; ++p) {
        const int e = p * 256 + tid;      // 128 8B-chunks per row
        const int row = e >> 7, ch = e & 127;
        *(u64*)(sH + row * LDH + ch * 4) = v[p];
      }
    }
    __syncthreads();

    // ---- prefetch x_{s+1}, mask, slot into registers (hides ids->emb chain) ----
    float4 px0, px1; float pm = 0.f; int pslot = -1;
    if (s + 1 < TT) {
      const int tn = dir ? (TT - 2 - s) : (s + 1);
      const int b = grp * BG + xrow;
      const int idx = ids[b * TT + tn];
      px0 = *(const float4*)(emb + (size_t)idx * EE + xc0);
      px1 = *(const float4*)(emb + (size_t)idx * EE + xc0 + 4);
      if (tid < BG) {
        const int b2 = grp * BG + tid;
        pm = (float)maskI[b2 * TT + tn];
        pslot = slotmap[b2 * TT + tn];
      }
    }

    // ---- gates = h @ Whh^T + x @ Wih^T (2 accumulation chains) ----
    floatx4 acc0 = {0.f, 0.f, 0.f, 0.f};
    floatx4 acc1 = {0.f, 0.f, 0.f, 0.f};
    const f16* aH = sH + rloc * LDH + kg * 8;
    #pragma unroll
    for (int kk = 0; kk < 16; kk += 2) {
      f16x8 a0 = *(const f16x8*)(aH + kk * 32);
      f16x8 a1 = *(const f16x8*)(aH + (kk + 1) * 32);
      acc0 = __builtin_amdgcn_mfma_f32_16x16x32_f16(a0, wh[kk], acc0, 0, 0, 0);
      acc1 = __builtin_amdgcn_mfma_f32_16x16x32_f16(a1, wh[kk + 1], acc1, 0, 0, 0);
    }
    const f16* aX = sX + rloc * LDE + kg * 8;
    #pragma unroll
    for (int kk = 0; kk < 4; kk += 2) {
      f16x8 a0 = *(const f16x8*)(aX + kk * 32);
      f16x8 a1 = *(const f16x8*)(aX + (kk + 1) * 32);
      acc0 = __builtin_amdgcn_mfma_f32_16x16x32_f16(a0, wx[kk], acc0, 0, 0, 0);
      acc1 = __builtin_amdgcn_mfma_f32_16x16x32_f16(a1, wx[kk + 1], acc1, 0, 0, 0);
    }
    floatx4 acc = acc0 + acc1;

    // ---- epilogue: quad-exchange gate types, LSTM cell update ----
    #pragma unroll
    for (int i = 0; i < 4; ++i) {
      const float g0 = acc[i] + bsc;
      const float s1 = __shfl_xor(g0, 1, 64);
      const float s2 = __shfl_xor(g0, 2, 64);
      const float s3 = __shfl_xor(s1, 2, 64);
      float vi, vf, vg, vo;
      if (q == 0)      { vi = g0; vf = s1; vg = s2; vo = s3; }
      else if (q == 1) { vi = s1; vf = g0; vg = s3; vo = s2; }
      else if (q == 2) { vi = s2; vf = s3; vg = g0; vo = s1; }
      else             { vi = s3; vf = s2; vg = s1; vo = g0; }
      const float ig = sigmf(vi);
      const float fg = sigmf(vf);
      const float gt = tanhfast(vg);
      const float og = sigmf(vo);
      const float cn = fg * cc[i] + ig * gt;
      const float hn = og * tanhfast(cn);
      const float m = sMask[mbase + i];
      cc[i] = m > 0.f ? cn : cc[i];
      float hk = m > 0.f ? hn : hh[i];
      const f16 h16 = (f16)hk;            // round state to fp16 so all consumers agree
      hh[i] = (float)h16;
    }
    {
      const float hq_ = (q == 0) ? hh[0] : (q == 1) ? hh[1] : (q == 2) ? hh[2] : hh[3];
      hOut[(mbase + q) * JW + jloc] = (f16)hq_;
    }
    __syncthreads();

    // ---- wave0 exports slice ----
    if (tid < 64) {
      const int bl = tid >> 2;             // batch 0..15
      const int c0 = (tid & 3) * 4;        // 4 f16 = 8B
      const u64 v = *(const u64*)(hOut + bl * JW + c0);
      u64* hdst = (u64*)(h_g + ((size_t)((((s + 1) & 1) * 2 + dir) * NGRP + grp) * BG + bl) * HH
                         + slice * JW + c0);
      if (FASTM) *hdst = v;                // plain -> lands in local XCD L2
      else __hip_atomic_store(hdst, v, __ATOMIC_RELAXED, __HIP_MEMORY_SCOPE_AGENT);
      const int slot = sSlot[bl];
      if (slot >= 0) {
        const u64 hv = sMask[bl] > 0.f ? v : 0ULL;   // ys = h * m
        *(u64*)(hist + ((size_t)(dir * BB + grp * BG + bl) * NSLOT + slot) * HH
                + slice * JW + c0) = hv;
      }
    }

    if (s + 1 < TT) {
      asm volatile("s_waitcnt vmcnt(0)" ::: "memory");   // data stores acked before flag
      unsigned* myflag = flags + (dom * 32 + slice) * 32;
      if (tid == 0) {
        if (FASTM) __hip_atomic_store(myflag, (unsigned)(s + 1),
                                      __ATOMIC_RELAXED, __HIP_MEMORY_SCOPE_WORKGROUP);
        else       __hip_atomic_store(myflag, (unsigned)(s + 1),
                                      __ATOMIC_RELAXED, __HIP_MEMORY_SCOPE_AGENT);
      }
      const unsigned tgt = (unsigned)(s + 1);
      const unsigned* fl = flags + (dom * 32 + (lane & 31)) * 32;
      if (FASTM) {
        for (;;) {
          const unsigned v = ld_sc0_u32(fl);
          if (__all(v >= tgt)) break;
        }
      } else {
        for (;;) {
          const unsigned v = __hip_atomic_load(fl, __ATOMIC_RELAXED, __HIP_MEMORY_SCOPE_AGENT);
          if (__all(v >= tgt)) break;
          __builtin_amdgcn_s_sleep(1);
        }
      }
      __builtin_amdgcn_sched_barrier(0);
      asm volatile("" ::: "memory");       // no h_g load hoisting above the poll

      // ---- commit prefetched x/mask/slot for step s+1 ----
      {
        f16x8 xv;
        xv[0]=(f16)px0.x; xv[1]=(f16)px0.y; xv[2]=(f16)px0.z; xv[3]=(f16)px0.w;
        xv[4]=(f16)px1.x; xv[5]=(f16)px1.y; xv[6]=(f16)px1.z; xv[7]=(f16)px1.w;
        *(f16x8*)(sX + xrow * LDE + xc0) = xv;
        if (tid < BG) { sMask[tid] = pm; sSlot[tid] = pslot; }
      }
    }
  }
}

// ---------------- gather boundary outputs ----------------
__global__ __launch_bounds__(256) void gather_out(
    const int* __restrict__ bnd, const int* __restrict__ slotmap,
    const f16* __restrict__ hist, float* __restrict__ out)
{
  const int bw = blockIdx.x;
  const int b = bw >> 6;
  const int w = bw & 63;
  const int k = threadIdx.x * 8;
  const int iv = bnd[b * 65 + w];
  const int jv = bnd[b * 65 + w + 1];
  const bool valid = (iv != -1) && (jv != -1);
  float* dst = out + (size_t)bw * 2048 + k;
  if (valid) {
    const int seg = k >> 9;                    // 0:h_f(i) 1:h_b(i) 2:h_f(j) 3:h_b(j)
    int ts = (seg < 2) ? iv : jv;
    ts = ts < 0 ? 0 : (ts > TT - 1 ? TT - 1 : ts);
    const int dirn = seg & 1;
    const int slot = slotmap[b * TT + ts];
    const f16* src = hist + ((size_t)(dirn * BB + b) * NSLOT + slot) * HH + (k & 511);
    f16x8 v = *(const f16x8*)src;
    float4 o0 = make_float4((float)v[0], (float)v[1], (float)v[2], (float)v[3]);
    float4 o1 = make_float4((float)v[4], (float)v[5], (float)v[6], (float)v[7]);
    *(float4*)dst = o0;
    *(float4*)(dst + 4) = o1;
  } else {
    float4 z = make_float4(0.f, 0.f, 0.f, 0.f);
    *(float4*)dst = z;
    *(float4*)(dst + 4) = z;
  }
}

extern "C" void kernel_launch(void* const* d_in, const int* in_sizes, int n_in,
                              void* d_out, int out_size, void* d_ws, size_t ws_size,
                              hipStream_t stream)
{
  (void)in_sizes; (void)n_in; (void)out_size; (void)ws_size;
  const int* ids     = (const int*)d_in[0];
  const int* maskI   = (const int*)d_in[1];
  const int* bnd     = (const int*)d_in[2];
  const float* emb   = (const float*)d_in[3];
  const float* Wih_f = (const float*)d_in[4];
  const float* Whh_f = (const float*)d_in[5];
  const float* b_f   = (const float*)d_in[6];
  const float* Wih_b = (const float*)d_in[7];
  const float* Whh_b = (const float*)d_in[8];
  const float* b_b   = (const float*)d_in[9];

  char* ws = (char*)d_ws;
  unsigned* flags = (unsigned*)ws;                    // 8*32 slots * 128B = 32KB
  unsigned* hsb   = (unsigned*)(ws + 32768);          // 32KB handshake slots
  unsigned* probe = (unsigned*)(ws + 65536);          // 1KB probe lines
  int* slotmap    = (int*)(ws + 69632);               // 128KB
  f16* h_g        = (f16*)(ws + 69632 + 131072);      // 256KB
  f16* hist       = (f16*)(ws + 69632 + 131072 + 262144);  // ~16.5MB

  hipMemsetAsync(ws, 0, 69632, stream);               // flags + handshake + probe
  build_map<<<dim3(BB), dim3(64), 0, stream>>>(bnd, slotmap);
  lstm_scan<<<dim3(256), dim3(256), 0, stream>>>(ids, maskI, emb,
      Wih_f, Whh_f, b_f, Wih_b, Whh_b, b_b, slotmap, h_g, hist, flags, hsb, probe);
  gather_out<<<dim3(BB * 64), dim3(256), 0, stream>>>(bnd, slotmap, hist, (float*)d_out);
}